// Round 11
// baseline (77.906 us; speedup 1.0000x reference)
//
#include <hip/hip_runtime.h>
#include <math.h>

#define B 1024
#define E 256
#define H 4
#define DH 64
#define L 192
#define NF 16384
#define NO 49152
#define BPB 2   // batches per block

// ---------------------------------------------------------------------------
// Kernel 0 (prep): blocks 0..191 transpose Wq, Wv, Wo into WT (WT[j][o]=W[o][j]);
// blocks 192..196 compute per-batch start offsets by binary search.
// ---------------------------------------------------------------------------
__global__ __launch_bounds__(256) void prep_kernel(
    const int* __restrict__ fb, const int* __restrict__ ob,
    int* __restrict__ start_f, int* __restrict__ start_o,
    const float* __restrict__ ipw, const float* __restrict__ opw,
    float* __restrict__ WT)
{
  int blk = blockIdx.x;
  if (blk < 192) {
    int m = blk / 64;                 // 0=Wq, 1=Wv, 2=Wo
    int r = blk % 64;
    int bx = (r & 7) * 32, by = (r >> 3) * 32;
    const float* src = (m == 0) ? ipw : (m == 1 ? ipw + 2 * E * E : opw);
    float* dst = WT + (size_t)m * E * E;
    __shared__ float tile[32][33];
    int tx = threadIdx.x & 31, ty = threadIdx.x >> 5;   // 32 x 8
#pragma unroll
    for (int i = 0; i < 32; i += 8)
      tile[ty + i][tx] = src[(size_t)(by + ty + i) * E + bx + tx];
    __syncthreads();
#pragma unroll
    for (int i = 0; i < 32; i += 8)
      dst[(size_t)(bx + ty + i) * E + by + tx] = tile[tx][ty + i];
  } else {
    int b = (blk - 192) * 256 + threadIdx.x;
    if (b > B) return;
    int lo = 0, hi = NF;
    while (lo < hi) { int m = (lo + hi) >> 1; if (fb[m] < b) lo = m + 1; else hi = m; }
    start_f[b] = lo;
    lo = 0; hi = NO;
    while (lo < hi) { int m = (lo + hi) >> 1; if (ob[m] < b) lo = m + 1; else hi = m; }
    start_o[b] = lo;
  }
}

// ---------------------------------------------------------------------------
// Fused kernel: 2 batches/block, 512 threads (8 waves), grid 512 (2 blocks/CU).
// Phases: q -> Y/sb -> X-stream (online softmax, 4 waves/batch)
//         -> Z-merge+attnw -> ctx -> out+residual+LN.
// LDS ~52 KB: un_s (32KB) is time-multiplexed as {q-partials, Y-partials,
// Z-partials, ctx-partials, out-partials}; YZ_s holds Y then Z.
// ---------------------------------------------------------------------------
__global__ __launch_bounds__(512, 4) void fused_kernel(
    const float* __restrict__ scene,
    const float* __restrict__ face, const float* __restrict__ obj,
    const float* __restrict__ ipw, const float* __restrict__ ipb,
    const float* __restrict__ WqT, const float* __restrict__ WvT,
    const float* __restrict__ WoT, const float* __restrict__ opb,
    const float* __restrict__ gamma, const float* __restrict__ beta,
    const int* __restrict__ start_f, const int* __restrict__ start_o,
    float* __restrict__ fusedO, float* __restrict__ attnw)
{
  int b0 = blockIdx.x * BPB;
  int t = threadIdx.x, wave = t >> 6, lane = t & 63;

  __shared__ float sc_s[BPB][E];        // 2 KB
  __shared__ float q_s[BPB][E];         // 2 KB (reused as x)
  __shared__ float YZ_s[BPB][H][E];     // 8 KB  (Y, then Z)
  __shared__ float ctx_s[BPB][E];       // 2 KB
  __shared__ float s_s[BPB][H][L];      // 6 KB  raw scores
  __shared__ float un_s[8192];          // 32 KB time-multiplexed scratch
  __shared__ float mw_s[BPB][4][H], su_s[BPB][4][H], sb_s[BPB][H];
  __shared__ int   info_s[BPB][4];      // sf0, so0, n_f, n

  for (int i = t; i < BPB * E; i += 512)
    ((float*)sc_s)[i] = scene[(size_t)b0 * E + i];
  if (t < BPB) {
    int b = b0 + t;
    int sf0 = start_f[b], cf = start_f[b + 1] - sf0;
    int so0 = start_o[b], co = start_o[b + 1] - so0;
    info_s[t][0] = sf0; info_s[t][1] = so0;
    info_s[t][2] = min(cf, L); info_s[t][3] = min(cf + co, L);
  }
  __syncthreads();

  // ---- q partials: wave covers j in [32w, 32w+32); lane owns outputs 4l..4l+3
  {
    const float4* W4 = (const float4*)WqT + lane;
    float4 a0 = {0,0,0,0}, a1 = {0,0,0,0};
    int j0 = wave * 32;
#pragma unroll
    for (int jj = 0; jj < 32; ++jj) {
      int j = j0 + jj;
      float4 w = W4[(size_t)j * 64];
      float s0 = sc_s[0][j], s1 = sc_s[1][j];
      a0.x += s0*w.x; a0.y += s0*w.y; a0.z += s0*w.z; a0.w += s0*w.w;
      a1.x += s1*w.x; a1.y += s1*w.y; a1.z += s1*w.z; a1.w += s1*w.w;
    }
    // part(w, bi, e) = un_s[(w*2+bi)*256 + e]
    *(float4*)&un_s[((wave * 2 + 0) << 8) + 4 * lane] = a0;
    *(float4*)&un_s[((wave * 2 + 1) << 8) + 4 * lane] = a1;
  }
  __syncthreads();
  for (int i = t; i < BPB * E; i += 512) {
    int bi = i >> 8, e = i & 255;
    float v = ipb[e];
#pragma unroll
    for (int w = 0; w < 8; ++w) v += un_s[((w * 2 + bi) << 8) + e];
    q_s[bi][e] = v;
  }
  __syncthreads();

  // ---- sb[b][h] = q_h · bk_h  (waves 0..1, one batch each)
  if (wave < BPB) {
#pragma unroll
    for (int h = 0; h < H; ++h) {
      float v = q_s[wave][h * DH + lane] * ipb[E + h * DH + lane];
#pragma unroll
      for (int o = 32; o; o >>= 1) v += __shfl_xor(v, o);
      if (lane == 0) sb_s[wave][h] = v;
    }
  }

  // ---- Y partials: wave -> (h = wave>>1, d-range = (wave&1)*32)
  {
    const float* Wk = ipw + (size_t)E * E;
    int h = wave >> 1, d0 = (wave & 1) * 32, wi = wave & 1;
    float4 a0 = {0,0,0,0}, a1 = {0,0,0,0};
#pragma unroll
    for (int dd = 0; dd < 32; ++dd) {
      int d = d0 + dd;
      float4 w = *((const float4*)(Wk + (size_t)(h * DH + d) * E) + lane);
      float q0 = q_s[0][h * DH + d], q1 = q_s[1][h * DH + d];
      a0.x += q0*w.x; a0.y += q0*w.y; a0.z += q0*w.z; a0.w += q0*w.w;
      a1.x += q1*w.x; a1.y += q1*w.y; a1.z += q1*w.z; a1.w += q1*w.w;
    }
    // Yp(wi, bi, h, e) = un_s[wi*4096 + (bi*4+h)*256 + e]
    *(float4*)&un_s[wi * 4096 + ((0 * 4 + h) << 8) + 4 * lane] = a0;
    *(float4*)&un_s[wi * 4096 + ((1 * 4 + h) << 8) + 4 * lane] = a1;
  }
  __syncthreads();
  for (int i = t; i < BPB * H * E; i += 512)        // Y = half0 + half1
    ((float*)YZ_s)[i] = un_s[i] + un_s[4096 + i];
  __syncthreads();

  // ---- X-stream: 4 waves per batch (bb = wave>>2, wi = wave&3)
  {
    int bb = wave >> 2, wi = wave & 3;
    int sf0 = info_s[bb][0], so0 = info_s[bb][1];
    int n_f = info_s[bb][2], n = info_s[bb][3];

    float4 y0 = *(const float4*)&YZ_s[bb][0][4 * lane];
    float4 y1 = *(const float4*)&YZ_s[bb][1][4 * lane];
    float4 y2 = *(const float4*)&YZ_s[bb][2][4 * lane];
    float4 y3 = *(const float4*)&YZ_s[bb][3][4 * lane];
    float sb0 = sb_s[bb][0], sb1 = sb_s[bb][1], sb2 = sb_s[bb][2], sb3 = sb_s[bb][3];

    float m0 = -3.0e38f, m1 = -3.0e38f, m2 = -3.0e38f, m3 = -3.0e38f;
    float u0 = 0.f, u1 = 0.f, u2 = 0.f, u3 = 0.f;
    float4 acc0 = {0,0,0,0}, acc1 = {0,0,0,0}, acc2 = {0,0,0,0}, acc3 = {0,0,0,0};

    float4 x4 = {0,0,0,0};
    if (wi < n) {
      const float* xrow = (wi < n_f) ? face + (size_t)(sf0 + wi) * E
                                     : obj  + (size_t)(so0 + wi - n_f) * E;
      x4 = ((const float4*)xrow)[lane];
    }
    for (int s = wi; s < n; s += 4) {
      float4 xn = {0,0,0,0};
      int sn = s + 4;
      if (sn < n) {
        const float* xrow = (sn < n_f) ? face + (size_t)(sf0 + sn) * E
                                       : obj  + (size_t)(so0 + sn - n_f) * E;
        xn = ((const float4*)xrow)[lane];
      }
      float p0 = x4.x*y0.x + x4.y*y0.y + x4.z*y0.z + x4.w*y0.w;
      float p1 = x4.x*y1.x + x4.y*y1.y + x4.z*y1.z + x4.w*y1.w;
      float p2 = x4.x*y2.x + x4.y*y2.y + x4.z*y2.z + x4.w*y2.w;
      float p3 = x4.x*y3.x + x4.y*y3.y + x4.z*y3.z + x4.w*y3.w;
#pragma unroll
      for (int o = 32; o; o >>= 1) {
        p0 += __shfl_xor(p0, o); p1 += __shfl_xor(p1, o);
        p2 += __shfl_xor(p2, o); p3 += __shfl_xor(p3, o);
      }
      p0 = (p0 + sb0) * 0.125f;
      p1 = (p1 + sb1) * 0.125f;
      p2 = (p2 + sb2) * 0.125f;
      p3 = (p3 + sb3) * 0.125f;
      if (lane == 0) {
        s_s[bb][0][s] = p0; s_s[bb][1][s] = p1;
        s_s[bb][2][s] = p2; s_s[bb][3][s] = p3;
      }
      if (p0 > m0) {
        float f = __expf(m0 - p0);
        acc0.x = acc0.x*f + x4.x; acc0.y = acc0.y*f + x4.y;
        acc0.z = acc0.z*f + x4.z; acc0.w = acc0.w*f + x4.w;
        u0 = u0*f + 1.f; m0 = p0;
      } else {
        float e = __expf(p0 - m0);
        acc0.x += e*x4.x; acc0.y += e*x4.y; acc0.z += e*x4.z; acc0.w += e*x4.w;
        u0 += e;
      }
      if (p1 > m1) {
        float f = __expf(m1 - p1);
        acc1.x = acc1.x*f + x4.x; acc1.y = acc1.y*f + x4.y;
        acc1.z = acc1.z*f + x4.z; acc1.w = acc1.w*f + x4.w;
        u1 = u1*f + 1.f; m1 = p1;
      } else {
        float e = __expf(p1 - m1);
        acc1.x += e*x4.x; acc1.y += e*x4.y; acc1.z += e*x4.z; acc1.w += e*x4.w;
        u1 += e;
      }
      if (p2 > m2) {
        float f = __expf(m2 - p2);
        acc2.x = acc2.x*f + x4.x; acc2.y = acc2.y*f + x4.y;
        acc2.z = acc2.z*f + x4.z; acc2.w = acc2.w*f + x4.w;
        u2 = u2*f + 1.f; m2 = p2;
      } else {
        float e = __expf(p2 - m2);
        acc2.x += e*x4.x; acc2.y += e*x4.y; acc2.z += e*x4.z; acc2.w += e*x4.w;
        u2 += e;
      }
      if (p3 > m3) {
        float f = __expf(m3 - p3);
        acc3.x = acc3.x*f + x4.x; acc3.y = acc3.y*f + x4.y;
        acc3.z = acc3.z*f + x4.z; acc3.w = acc3.w*f + x4.w;
        u3 = u3*f + 1.f; m3 = p3;
      } else {
        float e = __expf(p3 - m3);
        acc3.x += e*x4.x; acc3.y += e*x4.y; acc3.z += e*x4.z; acc3.w += e*x4.w;
        u3 += e;
      }
      x4 = xn;
    }
    // Zp(bb, wi, h, e) = un_s[bb*4096 + wi*1024 + h*256 + e]
    *(float4*)&un_s[bb * 4096 + wi * 1024 + (0 << 8) + 4 * lane] = acc0;
    *(float4*)&un_s[bb * 4096 + wi * 1024 + (1 << 8) + 4 * lane] = acc1;
    *(float4*)&un_s[bb * 4096 + wi * 1024 + (2 << 8) + 4 * lane] = acc2;
    *(float4*)&un_s[bb * 4096 + wi * 1024 + (3 << 8) + 4 * lane] = acc3;
    if (lane == 0) {
      mw_s[bb][wi][0] = m0; mw_s[bb][wi][1] = m1;
      mw_s[bb][wi][2] = m2; mw_s[bb][wi][3] = m3;
      su_s[bb][wi][0] = u0; su_s[bb][wi][1] = u1;
      su_s[bb][wi][2] = u2; su_s[bb][wi][3] = u3;
    }
  }
  __syncthreads();

  // ---- merge Z (4 wave-partials) into YZ_s
  for (int i = t; i < BPB * H * E; i += 512) {
    int bi = i >> 10, rem = i & 1023, h = rem >> 8;
    float z = 0.f;
    if (info_s[bi][3] > 0) {
      float ma = mw_s[bi][0][h], mb = mw_s[bi][1][h];
      float mc = mw_s[bi][2][h], md = mw_s[bi][3][h];
      float M = fmaxf(fmaxf(ma, mb), fmaxf(mc, md));
      float fa = __expf(ma - M), fb = __expf(mb - M);
      float fc = __expf(mc - M), fd = __expf(md - M);
      float inv = 1.0f / (fa * su_s[bi][0][h] + fb * su_s[bi][1][h] +
                          fc * su_s[bi][2][h] + fd * su_s[bi][3][h]);
      z = (fa * un_s[bi * 4096 + 0 * 1024 + rem] +
           fb * un_s[bi * 4096 + 1 * 1024 + rem] +
           fc * un_s[bi * 4096 + 2 * 1024 + rem] +
           fd * un_s[bi * 4096 + 3 * 1024 + rem]) * inv;
    }
    ((float*)YZ_s)[i] = z;
  }
  // ---- attnw (BPB*L = 384 <= 512)
  if (t < BPB * L) {
    int bi = t / L, s = t - bi * L;
    int n = info_s[bi][3];
    float v;
    if (n == 0) v = 1.0f / L;
    else if (s < n) {
      v = 0.f;
#pragma unroll
      for (int h = 0; h < H; ++h) {
        float ma = mw_s[bi][0][h], mb = mw_s[bi][1][h];
        float mc = mw_s[bi][2][h], md = mw_s[bi][3][h];
        float M = fmaxf(fmaxf(ma, mb), fmaxf(mc, md));
        float fa = __expf(ma - M), fb = __expf(mb - M);
        float fc = __expf(mc - M), fd = __expf(md - M);
        float inv = 1.0f / (fa * su_s[bi][0][h] + fb * su_s[bi][1][h] +
                            fc * su_s[bi][2][h] + fd * su_s[bi][3][h]);
        v += __expf(s_s[bi][h][s] - M) * inv;
      }
      v *= 0.25f;
    } else v = 0.f;
    attnw[(size_t)(b0 + bi) * L + s] = v;
  }
  __syncthreads();

  // ---- ctx partials: wave covers j in [32w,32w+32); head(4l..4l+3) = l>>4
  {
    const float4* W4 = (const float4*)WvT + lane;
    int j0 = wave * 32, hoff = (lane >> 4) * E;
    float4 a0 = {0,0,0,0}, a1 = {0,0,0,0};
#pragma unroll
    for (int jj = 0; jj < 32; ++jj) {
      int j = j0 + jj;
      float4 w = W4[(size_t)j * 64];
      float z0 = ((float*)YZ_s[0])[hoff + j];
      float z1 = ((float*)YZ_s[1])[hoff + j];
      a0.x += z0*w.x; a0.y += z0*w.y; a0.z += z0*w.z; a0.w += z0*w.w;
      a1.x += z1*w.x; a1.y += z1*w.y; a1.z += z1*w.z; a1.w += z1*w.w;
    }
    *(float4*)&un_s[((wave * 2 + 0) << 8) + 4 * lane] = a0;
    *(float4*)&un_s[((wave * 2 + 1) << 8) + 4 * lane] = a1;
  }
  __syncthreads();
  for (int i = t; i < BPB * E; i += 512) {
    int bi = i >> 8, e = i & 255;
    float v = ipb[2 * E + e];
#pragma unroll
    for (int w = 0; w < 8; ++w) v += un_s[((w * 2 + bi) << 8) + e];
    ctx_s[bi][e] = v;
  }
  __syncthreads();

  // ---- out-proj partials
  {
    const float4* W4 = (const float4*)WoT + lane;
    int j0 = wave * 32;
    float4 a0 = {0,0,0,0}, a1 = {0,0,0,0};
#pragma unroll
    for (int jj = 0; jj < 32; ++jj) {
      int j = j0 + jj;
      float4 w = W4[(size_t)j * 64];
      float c0 = ctx_s[0][j], c1 = ctx_s[1][j];
      a0.x += c0*w.x; a0.y += c0*w.y; a0.z += c0*w.z; a0.w += c0*w.w;
      a1.x += c1*w.x; a1.y += c1*w.y; a1.z += c1*w.z; a1.w += c1*w.w;
    }
    *(float4*)&un_s[((wave * 2 + 0) << 8) + 4 * lane] = a0;
    *(float4*)&un_s[((wave * 2 + 1) << 8) + 4 * lane] = a1;
  }
  __syncthreads();
  for (int i = t; i < BPB * E; i += 512) {
    int bi = i >> 8, e = i & 255;
    float v = opb[e] + sc_s[bi][e];
#pragma unroll
    for (int w = 0; w < 8; ++w) v += un_s[((w * 2 + bi) << 8) + e];
    q_s[bi][e] = v;                    // reuse q_s as x
  }
  __syncthreads();

  // ---- LayerNorm: waves 0..1, one batch each (in-wave over 256 values)
  if (wave < BPB) {
    float v0 = q_s[wave][lane], v1 = q_s[wave][lane + 64],
          v2 = q_s[wave][lane + 128], v3 = q_s[wave][lane + 192];
    float s1 = v0 + v1 + v2 + v3;
#pragma unroll
    for (int o = 32; o; o >>= 1) s1 += __shfl_xor(s1, o);
    float mu = s1 * (1.0f / E);
    float d0 = v0 - mu, d1 = v1 - mu, d2 = v2 - mu, d3 = v3 - mu;
    float s2 = d0*d0 + d1*d1 + d2*d2 + d3*d3;
#pragma unroll
    for (int o = 32; o; o >>= 1) s2 += __shfl_xor(s2, o);
    float inv = 1.0f / sqrtf(s2 * (1.0f / E) + 1e-5f);
    size_t base = (size_t)(b0 + wave) * E;
    fusedO[base + lane      ] = d0 * inv * gamma[lane      ] + beta[lane      ];
    fusedO[base + lane +  64] = d1 * inv * gamma[lane +  64] + beta[lane +  64];
    fusedO[base + lane + 128] = d2 * inv * gamma[lane + 128] + beta[lane + 128];
    fusedO[base + lane + 192] = d3 * inv * gamma[lane + 192] + beta[lane + 192];
  }
}

// ---------------------------------------------------------------------------
extern "C" void kernel_launch(void* const* d_in, const int* in_sizes, int n_in,
                              void* d_out, int out_size, void* d_ws, size_t ws_size,
                              hipStream_t stream) {
  const float* scene = (const float*)d_in[0];
  const float* face  = (const float*)d_in[1];
  const float* obj   = (const float*)d_in[2];
  const int*   fb    = (const int*)d_in[3];
  const int*   ob    = (const int*)d_in[4];
  const float* ipw   = (const float*)d_in[5];
  const float* ipb   = (const float*)d_in[6];
  const float* opw   = (const float*)d_in[7];
  const float* opb   = (const float*)d_in[8];
  const float* gam   = (const float*)d_in[9];
  const float* bet   = (const float*)d_in[10];

  float* fused = (float*)d_out;
  float* attnw = fused + (size_t)B * E;

  // ws: starts (16KB) | WT (768KB)
  int* start_f = (int*)d_ws;
  int* start_o = start_f + (B + 1);
  float* WT   = (float*)((char*)d_ws + (16 << 10));
  float* WqT = WT;
  float* WvT = WT + (size_t)E * E;
  float* WoT = WT + (size_t)2 * E * E;

  prep_kernel<<<197, 256, 0, stream>>>(fb, ob, start_f, start_o, ipw, opw, WT);
  fused_kernel<<<B / BPB, 512, 0, stream>>>(scene, face, obj, ipw, ipb,
                                            WqT, WvT, WoT, opb, gam, bet,
                                            start_f, start_o, fused, attnw);
}